// Round 10
// baseline (268.648 us; speedup 1.0000x reference)
//
#include <hip/hip_runtime.h>
#include <hip/hip_bf16.h>
#include <math.h>

#define NB    4
#define NC    128
#define NPIX  3136      // 56*56
#define CHW   401408    // 128*3136
#define SKS   68        // padded LDS row stride for K/V images
#define STS   19        // conv transpose-buffer row stride (odd => bank-clean)

// ---------- DPP wave64 reduce helpers (VALU pipe, no DS) -------------------
template <int CTRL, int RM>
__device__ __forceinline__ float dpp_mov(float x, float old) {
    return __int_as_float(__builtin_amdgcn_update_dpp(
        __float_as_int(old), __float_as_int(x), CTRL, RM, 0xf, false));
}
__device__ __forceinline__ float wave_max(float x) {
    x = fmaxf(x, dpp_mov<0x111, 0xf>(x, x));   // row_shr:1
    x = fmaxf(x, dpp_mov<0x112, 0xf>(x, x));   // row_shr:2
    x = fmaxf(x, dpp_mov<0x114, 0xf>(x, x));   // row_shr:4
    x = fmaxf(x, dpp_mov<0x118, 0xf>(x, x));   // row_shr:8
    x = fmaxf(x, dpp_mov<0x142, 0xa>(x, x));   // row_bcast:15 -> rows 1,3
    x = fmaxf(x, dpp_mov<0x143, 0xc>(x, x));   // row_bcast:31 -> rows 2,3
    return __int_as_float(__builtin_amdgcn_readlane(__float_as_int(x), 63));
}
__device__ __forceinline__ float wave_sum(float x) {
    x = x + dpp_mov<0x111, 0xf>(x, 0.f);
    x = x + dpp_mov<0x112, 0xf>(x, 0.f);
    x = x + dpp_mov<0x114, 0xf>(x, 0.f);
    x = x + dpp_mov<0x118, 0xf>(x, 0.f);
    x = x + dpp_mov<0x142, 0xa>(x, 0.f);
    x = x + dpp_mov<0x143, 0xc>(x, 0.f);
    return __int_as_float(__builtin_amdgcn_readlane(__float_as_int(x), 63));
}

// 16-term QK dot, 2 chains; kp2 = continuation pointer (handles row wrap)
__device__ __forceinline__ float qk16(const float* kp, const float* kp2,
                                      float4 r0, float4 r1, float4 r2, float4 r3) {
    float a0, a1;
    a0  = r0.x * kp[0];   a1  = r0.y * kp[1];
    a0 += r0.z * kp[2];   a1 += r0.w * kp[3];
    a0 += r1.x * kp[4];   a1 += r1.y * kp[5];
    a0 += r1.z * kp[6];   a1 += r1.w * kp[7];
    a0 += r2.x * kp2[0];  a1 += r2.y * kp2[1];
    a0 += r2.z * kp2[2];  a1 += r2.w * kp2[3];
    a0 += r3.x * kp2[4];  a1 += r3.y * kp2[5];
    a0 += r3.z * kp2[6];  a1 += r3.w * kp2[7];
    return a0 + a1;
}
__device__ __forceinline__ float sum16(float4 r0, float4 r1, float4 r2, float4 r3) {
    return (((r0.x + r0.y) + (r0.z + r0.w)) + ((r1.x + r1.y) + (r1.z + r1.w)))
         + (((r2.x + r2.y) + (r2.z + r2.w)) + ((r3.x + r3.y) + (r3.z + r3.w)));
}

// ---------------- prep: weight pack + rel sums ------------------------------
__global__ __launch_bounds__(256) void prep_kernel(
    const float* __restrict__ qw, const float* __restrict__ kw,
    const float* __restrict__ vw,
    const float* __restrict__ rel_h, const float* __restrict__ rel_w,
    float* __restrict__ w4q, float* __restrict__ w4k, float* __restrict__ w4v,
    float* __restrict__ rb)
{
    int idx = blockIdx.x * 256 + threadIdx.x;
    if (idx < 3 * 16384) {
        int m = idx >> 14;
        int r = idx & 16383;          // dst-linear: ((c4*128 + o)*4 + cc)
        int cc = r & 3;
        int t = r >> 2;
        int o = t & 127;
        int c4 = t >> 7;
        const float* src = (m == 0) ? qw : (m == 1) ? kw : vw;
        float* dst = (m == 0) ? w4q : (m == 1) ? w4k : w4v;
        dst[r] = src[o * 128 + c4 * 4 + cc];
    }
    if (idx < 14) {
        const float* src = (idx < 7) ? rel_h : rel_w;
        int off = (idx < 7) ? idx : idx - 7;
        float s = 0.f;
        for (int c = 0; c < 64; ++c) s += src[c * 7 + off];
        rb[idx] = s;
    }
}

// ---------------- conv: fused 1x1 convs Q,K,V (fp32) -----------------------
// r7 tile-16 structure + depth-2 A/B weight prefetch, xs batched at iter top.
// lane=o compute (coalesced W4 loads); stride-19 LDS transpose; lane=pixel
// coalesced stores to unpadded q/k/v.
__global__ __launch_bounds__(256) void conv_kernel(
    const float* __restrict__ x,
    const float* __restrict__ w4q, const float* __restrict__ w4k,
    const float* __restrict__ w4v,
    const float* __restrict__ qb, const float* __restrict__ kb,
    const float* __restrict__ vb,
    float* __restrict__ q, float* __restrict__ kbuf, float* __restrict__ vbuf)
{
    __shared__ float sx[128 * 16];       // [c][pix] 8KB
    __shared__ float st[3 * 128 * STS];  // q/k/v transpose planes, 28.5KB
    int bid = blockIdx.x;
    int tile = bid % 196;
    int b = bid / 196;
    int pix0 = tile * 16;
    const float* xb = x + b * CHW + pix0;

    for (int i = threadIdx.x; i < 512; i += 256) {
        int c = i >> 2, p4 = (i & 3) * 4;
        *(float4*)(sx + c * 16 + p4) = *(const float4*)(xb + c * NPIX + p4);
    }
    __syncthreads();

    int lane = threadIdx.x & 63;
    int wave = threadIdx.x >> 6;
    int o = wave * 32 + (lane & 31);
    int ph = (lane >> 5) * 8;
    const float4* Wq = (const float4*)w4q + o;
    const float4* Wk = (const float4*)w4k + o;
    const float4* Wv = (const float4*)w4v + o;

    // depth-2 software pipeline: A = even c4-block, B = odd
    float4 wqA = Wq[0],   wkA = Wk[0],   wvA = Wv[0];
    float4 wqB = Wq[128], wkB = Wk[128], wvB = Wv[128];
    float aq[8] = {}, ak[8] = {}, av[8] = {};
    #pragma unroll 1
    for (int c4 = 0; c4 < 32; c4 += 2) {
        // batched x reads for the whole pair (8 rows x 2 float4)
        float4 xs[16];
        #pragma unroll
        for (int r = 0; r < 8; ++r) {
            const float* xr = sx + (c4 * 4 + r) * 16 + ph;
            xs[2 * r]     = *(const float4*)xr;
            xs[2 * r + 1] = *(const float4*)(xr + 4);
        }
        int ia = ((c4 + 2) & 31) * 128;   // masked tail prefetch (harmless)
        int ib = ((c4 + 3) & 31) * 128;
        // ---- A: rows 0..3 ----
        {
            float wqr[4] = {wqA.x, wqA.y, wqA.z, wqA.w};
            float wkr[4] = {wkA.x, wkA.y, wkA.z, wkA.w};
            float wvr[4] = {wvA.x, wvA.y, wvA.z, wvA.w};
            #pragma unroll
            for (int cc = 0; cc < 4; ++cc) {
                float4 xa = xs[2 * cc], xc = xs[2 * cc + 1];
                float xv[8] = {xa.x, xa.y, xa.z, xa.w, xc.x, xc.y, xc.z, xc.w};
                #pragma unroll
                for (int p = 0; p < 8; ++p) {
                    aq[p] += wqr[cc] * xv[p];
                    ak[p] += wkr[cc] * xv[p];
                    av[p] += wvr[cc] * xv[p];
                }
            }
        }
        wqA = Wq[ia]; wkA = Wk[ia]; wvA = Wv[ia];   // reload after last use
        // ---- B: rows 4..7 ----
        {
            float wqr[4] = {wqB.x, wqB.y, wqB.z, wqB.w};
            float wkr[4] = {wkB.x, wkB.y, wkB.z, wkB.w};
            float wvr[4] = {wvB.x, wvB.y, wvB.z, wvB.w};
            #pragma unroll
            for (int cc = 0; cc < 4; ++cc) {
                float4 xa = xs[8 + 2 * cc], xc = xs[8 + 2 * cc + 1];
                float xv[8] = {xa.x, xa.y, xa.z, xa.w, xc.x, xc.y, xc.z, xc.w};
                #pragma unroll
                for (int p = 0; p < 8; ++p) {
                    aq[p] += wqr[cc] * xv[p];
                    ak[p] += wkr[cc] * xv[p];
                    av[p] += wvr[cc] * xv[p];
                }
            }
        }
        wqB = Wq[ib]; wkB = Wk[ib]; wvB = Wv[ib];
    }
    float bq = qb[o], bk = kb[o], bv = vb[o];
    float* wrq = st + o * STS + ph;
    float* wrk = st + 128 * STS + o * STS + ph;
    float* wrv = st + 2 * 128 * STS + o * STS + ph;
    #pragma unroll
    for (int p = 0; p < 8; ++p) {
        wrq[p] = aq[p] + bq;
        wrk[p] = ak[p] + bk;
        wrv[p] = av[p] + bv;
    }
    __syncthreads();

    int pix = threadIdx.x & 15;
    int o8 = (threadIdx.x >> 4) * 8;
    float* qd = q + b * CHW + pix0 + pix;
    float* kd = kbuf + b * CHW + pix0 + pix;
    float* vd = vbuf + b * CHW + pix0 + pix;
    #pragma unroll
    for (int i = 0; i < 8; ++i) {
        int r = o8 + i;
        qd[r * NPIX] = st[r * STS + pix];
        kd[r * NPIX] = st[128 * STS + r * STS + pix];
        vd[r * NPIX] = st[2 * 128 * STS + r * STS + pix];
    }
}

// ---------------- attn: per-(b,c,row-quarter), 2 groups/iter, 8 waves/SIMD -
// Twin chains (A,B adjacent groups) for ILP; VGPR forced <=64 via
// __launch_bounds__(256,8); uniform addressing hoisted to SGPRs.
__global__ __launch_bounds__(256, 8) void attn_kernel(
    const float* __restrict__ q, const float* __restrict__ kbuf,
    const float* __restrict__ vbuf,
    const float* __restrict__ kb, const float* __restrict__ vb,
    const float* __restrict__ rb, float* __restrict__ out)
{
    __shared__ float sK[20 * SKS];
    __shared__ float sV[21 * SKS];   // row 20 zeroed (read only with w=0)
    __shared__ float sW[4 * 128];    // per wave: [A 64][B 64]
    int bid = blockIdx.x;
    int qpart = bid & 3;
    int bc = bid >> 2;
    int ch = bc & 127;
    const float* qc = q + bc * NPIX + 784 * qpart;
    const float* kc = kbuf + bc * NPIX;
    const float* vc = vbuf + bc * NPIX;
    float* oc = out + bc * NPIX + 784 * qpart;
    float kbias = kb[ch], vbias = vb[ch];
    int qr0 = 14 * qpart;

    for (int i = threadIdx.x; i < 20 * 62; i += 256) {
        int yy = i / 62, xx = i - yy * 62;
        int gy = qr0 + yy - 3;
        int gx = xx - 3;
        bool in = (gy >= 0) && (gy < 56) && (gx >= 0) && (gx < 56);
        int off = in ? gy * 56 + gx : 0;
        float kv = in ? kc[off] : kbias;
        float vv = in ? vc[off] : vbias;
        sK[yy * SKS + xx] = kv;
        sV[yy * SKS + xx] = vv;
    }
    for (int i = threadIdx.x; i < SKS; i += 256) sV[20 * SKS + i] = 0.f;

    int lane = threadIdx.x & 63;
    int wave = threadIdx.x >> 6;
    int k2 = min(lane, 48);
    int di = k2 / 7, dj = k2 - di * 7;
    float rbias = rb[di] + rb[7 + dj];
    int koff = di * SKS + dj;
    int t16 = lane & 15, p = lane >> 4;
    float* sWA = sW + wave * 128;
    float* sWB = sWA + 64;

    // initial pair prefetch (global loads, no LDS dep -> before barrier)
    int ulA = wave * 32;
    int y0 = (ulA >= 56) ? 1 : 0;
    int x0 = ulA - y0 * 56;
    float4 a0 = *(const float4*)(qc + ulA);
    float4 a1 = *(const float4*)(qc + ulA + 4);
    float4 a2 = *(const float4*)(qc + ulA + 8);
    float4 a3 = *(const float4*)(qc + ulA + 12);
    float4 b0 = *(const float4*)(qc + ulA + 16);
    float4 b1 = *(const float4*)(qc + ulA + 20);
    float4 b2 = *(const float4*)(qc + ulA + 24);
    float4 b3 = *(const float4*)(qc + ulA + 28);
    __syncthreads();

    #pragma unroll 1
    for (int it = 0; it < 6; ++it) {
        // uniform (SGPR) addressing for the pair
        int wrapB = (x0 + 16 >= 56);
        int offA = __builtin_amdgcn_readfirstlane(y0 * SKS + x0);
        int offB = offA + (wrapB ? 28 : 16);              // == (yB*SKS + xB) - ...
        int xB = wrapB ? (x0 - 40) : (x0 + 16);
        int dA2 = (x0 == 48) ? 20 : 8;                    // kp2 delta (row wrap)
        int dB2 = (xB == 48) ? 20 : 8;

        const float* kpA = sK + offA + koff;
        const float* kpB = sK + offB + koff;

        float qsA = sum16(a0, a1, a2, a3);
        float qsB = sum16(b0, b1, b2, b3);
        float accA = qk16(kpA, kpA + dA2, a0, a1, a2, a3);
        float accB = qk16(kpB, kpB + dB2, b0, b1, b2, b3);
        float valA = (lane < 49) ? fmaf(qsA, rbias, accA) : -1e30f;
        float valB = (lane < 49) ? fmaf(qsB, rbias, accB) : -1e30f;

        int ulCur = ulA;
        // reload q regs for next pair (after last use; hidden under softmax/PV)
        if (it < 5) {
            int un = ulA + 128;
            a0 = *(const float4*)(qc + un);
            a1 = *(const float4*)(qc + un + 4);
            a2 = *(const float4*)(qc + un + 8);
            a3 = *(const float4*)(qc + un + 12);
            b0 = *(const float4*)(qc + un + 16);
            b1 = *(const float4*)(qc + un + 20);
            b2 = *(const float4*)(qc + un + 24);
            b3 = *(const float4*)(qc + un + 28);
        } else if (wave == 0) {   // tail: group 48 q into A regs
            a0 = *(const float4*)(qc + 768);
            a1 = *(const float4*)(qc + 772);
            a2 = *(const float4*)(qc + 776);
            a3 = *(const float4*)(qc + 780);
        }

        // twin softmax (independent DPP chains interleave on VALU)
        float mA = wave_max(valA);
        float mB = wave_max(valB);
        float eA = __expf(valA - mA);
        float eB = __expf(valB - mB);
        float sA = wave_sum(eA);
        float sB = wave_sum(eB);
        sWA[lane] = eA * __builtin_amdgcn_rcpf(sA);
        sWB[lane] = eB * __builtin_amdgcn_rcpf(sB);

        // twin PV (per-lane wrap select on t16)
        int wA = (x0 + t16 >= 56) ? (SKS - 56) : 0;
        int wB = (xB + t16 >= 56) ? (SKS - 56) : 0;
        const float* vbA = sV + offA + t16 + wA + p * (2 * SKS);
        const float* vbB = sV + offB + t16 + wB + p * (2 * SKS);
        const float* wbA = sWA + p * 14;
        const float* wbB = sWB + p * 14;
        float oA0 = 0.f, oA1 = 0.f, oB0 = 0.f, oB1 = 0.f;
        #pragma unroll
        for (int j = 0; j < 7; ++j) {
            oA0 += wbA[j] * vbA[j];
            oB0 += wbB[j] * vbB[j];
            oA1 += wbA[7 + j] * vbA[SKS + j];
            oB1 += wbB[7 + j] * vbB[SKS + j];
        }
        float oaccA = oA0 + oA1, oaccB = oB0 + oB1;
        oaccA += __shfl_xor(oaccA, 16);
        oaccB += __shfl_xor(oaccB, 16);
        oaccA += __shfl_xor(oaccA, 32);
        oaccB += __shfl_xor(oaccB, 32);
        if (lane < 16) {
            oc[ulCur + lane] = oaccA;
            oc[ulCur + 16 + lane] = oaccB;
        }

        ulA += 128; x0 += 16; y0 += 2;
        if (x0 >= 56) { x0 -= 56; ++y0; }
    }

    if (wave == 0) {   // group 48: (y,x) = (13,40); no wraps anywhere
        const float* kp = sK + 13 * SKS + 40 + koff;
        float qs = sum16(a0, a1, a2, a3);
        float acc = qk16(kp, kp + 8, a0, a1, a2, a3);
        float val = (lane < 49) ? fmaf(qs, rbias, acc) : -1e30f;
        float m = wave_max(val);
        float e = __expf(val - m);
        float s = wave_sum(e);
        sWA[lane] = e * __builtin_amdgcn_rcpf(s);
        const float* vb_ = sV + 13 * SKS + 40 + t16 + p * (2 * SKS);
        const float* wb_ = sWA + p * 14;
        float o0 = 0.f, o1 = 0.f;
        #pragma unroll
        for (int j = 0; j < 7; ++j) {
            o0 += wb_[j] * vb_[j];
            o1 += wb_[7 + j] * vb_[SKS + j];
        }
        float oacc = o0 + o1;
        oacc += __shfl_xor(oacc, 16);
        oacc += __shfl_xor(oacc, 32);
        if (lane < 16) oc[768 + lane] = oacc;
    }
}

extern "C" void kernel_launch(void* const* d_in, const int* in_sizes, int n_in,
                              void* d_out, int out_size, void* d_ws, size_t ws_size,
                              hipStream_t stream) {
    const float* x     = (const float*)d_in[0];
    const float* qw    = (const float*)d_in[1];
    const float* qb    = (const float*)d_in[2];
    const float* kw    = (const float*)d_in[3];
    const float* kb    = (const float*)d_in[4];
    const float* vw    = (const float*)d_in[5];
    const float* vb    = (const float*)d_in[6];
    const float* rel_h = (const float*)d_in[7];
    const float* rel_w = (const float*)d_in[8];
    float* out = (float*)d_out;

    float* ws   = (float*)d_ws;
    float* kbuf = ws;                    // 1605632
    float* vbuf = kbuf + 1605632;        // 1605632
    float* qbuf = vbuf + 1605632;        // 1605632
    float* w4q  = qbuf + 1605632;        // 16384
    float* w4k  = w4q + 16384;
    float* w4v  = w4k + 16384;
    float* rb   = w4v + 16384;           // 16

    prep_kernel<<<192, 256, 0, stream>>>(qw, kw, vw, rel_h, rel_w,
                                         w4q, w4k, w4v, rb);
    conv_kernel<<<784, 256, 0, stream>>>(x, w4q, w4k, w4v, qb, kb, vb,
                                         qbuf, kbuf, vbuf);
    attn_kernel<<<2048, 256, 0, stream>>>(qbuf, kbuf, vbuf, kb, vb, rb, out);
}

// Round 12
// 138.659 us; speedup vs baseline: 1.9375x; 1.9375x over previous
//
#include <hip/hip_runtime.h>
#include <hip/hip_bf16.h>
#include <math.h>

#define NB    4
#define NC    128
#define NPIX  3136      // 56*56
#define CHW   401408    // 128*3136
#define SKS   68        // padded LDS row stride for K/V images
#define STS   19        // conv transpose-buffer row stride (odd => bank-clean)

// ---------- DPP wave64 reduce helpers (VALU pipe, no DS) -------------------
template <int CTRL, int RM>
__device__ __forceinline__ float dpp_mov(float x, float old) {
    return __int_as_float(__builtin_amdgcn_update_dpp(
        __float_as_int(old), __float_as_int(x), CTRL, RM, 0xf, false));
}
__device__ __forceinline__ float wave_max(float x) {
    x = fmaxf(x, dpp_mov<0x111, 0xf>(x, x));   // row_shr:1
    x = fmaxf(x, dpp_mov<0x112, 0xf>(x, x));   // row_shr:2
    x = fmaxf(x, dpp_mov<0x114, 0xf>(x, x));   // row_shr:4
    x = fmaxf(x, dpp_mov<0x118, 0xf>(x, x));   // row_shr:8
    x = fmaxf(x, dpp_mov<0x142, 0xa>(x, x));   // row_bcast:15 -> rows 1,3
    x = fmaxf(x, dpp_mov<0x143, 0xc>(x, x));   // row_bcast:31 -> rows 2,3
    return __int_as_float(__builtin_amdgcn_readlane(__float_as_int(x), 63));
}
__device__ __forceinline__ float wave_sum(float x) {
    x = x + dpp_mov<0x111, 0xf>(x, 0.f);
    x = x + dpp_mov<0x112, 0xf>(x, 0.f);
    x = x + dpp_mov<0x114, 0xf>(x, 0.f);
    x = x + dpp_mov<0x118, 0xf>(x, 0.f);
    x = x + dpp_mov<0x142, 0xa>(x, 0.f);
    x = x + dpp_mov<0x143, 0xc>(x, 0.f);
    return __int_as_float(__builtin_amdgcn_readlane(__float_as_int(x), 63));
}

// ---------------- prep: weight pack + rel sums ------------------------------
__global__ __launch_bounds__(256) void prep_kernel(
    const float* __restrict__ qw, const float* __restrict__ kw,
    const float* __restrict__ vw,
    const float* __restrict__ rel_h, const float* __restrict__ rel_w,
    float* __restrict__ w4q, float* __restrict__ w4k, float* __restrict__ w4v,
    float* __restrict__ rb)
{
    int idx = blockIdx.x * 256 + threadIdx.x;
    if (idx < 3 * 16384) {
        int m = idx >> 14;
        int r = idx & 16383;          // dst-linear: ((c4*128 + o)*4 + cc)
        int cc = r & 3;
        int t = r >> 2;
        int o = t & 127;
        int c4 = t >> 7;
        const float* src = (m == 0) ? qw : (m == 1) ? kw : vw;
        float* dst = (m == 0) ? w4q : (m == 1) ? w4k : w4v;
        dst[r] = src[o * 128 + c4 * 4 + cc];
    }
    if (idx < 14) {
        const float* src = (idx < 7) ? rel_h : rel_w;
        int off = (idx < 7) ? idx : idx - 7;
        float s = 0.f;
        for (int c = 0; c < 64; ++c) s += src[c * 7 + off];
        rb[idx] = s;
    }
}

// ---------------- conv: fused 1x1 convs Q,K,V (fp32, split-o) --------------
// block = (b, 16-pixel tile, osplit of 64 outs). 4 waves; thread = (o, 4-pix
// group). Coalesced W4 loads w/ depth-2 A/B prefetch; per-c4 batched LDS
// reads; stride-19 LDS transpose; lane=pixel coalesced stores.
__global__ __launch_bounds__(256) void conv_kernel(
    const float* __restrict__ x,
    const float* __restrict__ w4q, const float* __restrict__ w4k,
    const float* __restrict__ w4v,
    const float* __restrict__ qb, const float* __restrict__ kb,
    const float* __restrict__ vb,
    float* __restrict__ q, float* __restrict__ kbuf, float* __restrict__ vbuf)
{
    __shared__ float sx[128 * 16];      // [c][pix] 8KB
    __shared__ float st[3 * 64 * STS];  // q/k/v transpose planes, 14.25KB
    int bid = blockIdx.x;
    int osplit = bid & 1;
    int tile = (bid >> 1) % 196;
    int b = bid / 392;
    int pix0 = tile * 16;
    const float* xb = x + b * CHW + pix0;

    for (int i = threadIdx.x; i < 512; i += 256) {
        int c = i >> 2, p4 = (i & 3) * 4;
        *(float4*)(sx + c * 16 + p4) = *(const float4*)(xb + c * NPIX + p4);
    }
    __syncthreads();

    int lane = threadIdx.x & 63;
    int wave = threadIdx.x >> 6;
    int olocal = (wave & 1) * 32 + (lane & 31);
    int o = osplit * 64 + olocal;
    int ph = ((wave >> 1) * 2 + (lane >> 5)) * 4;   // 0,4,8,12
    const float4* Wq = (const float4*)w4q + o;
    const float4* Wk = (const float4*)w4k + o;
    const float4* Wv = (const float4*)w4v + o;

    // depth-2 software pipeline: A = even c4-block, B = odd
    float4 wqA = Wq[0],   wkA = Wk[0],   wvA = Wv[0];
    float4 wqB = Wq[128], wkB = Wk[128], wvB = Wv[128];
    float aq[4] = {}, ak[4] = {}, av[4] = {};
    #pragma unroll 1
    for (int c4 = 0; c4 < 32; c4 += 2) {
        int ia = ((c4 + 2) & 31) * 128;   // masked tail prefetch (harmless)
        int ib = ((c4 + 3) & 31) * 128;
        // ---- A: rows 4*c4 .. 4*c4+3 ----
        {
            float4 xs[4];
            #pragma unroll
            for (int r = 0; r < 4; ++r)
                xs[r] = *(const float4*)(sx + (c4 * 4 + r) * 16 + ph);
            float wqr[4] = {wqA.x, wqA.y, wqA.z, wqA.w};
            float wkr[4] = {wkA.x, wkA.y, wkA.z, wkA.w};
            float wvr[4] = {wvA.x, wvA.y, wvA.z, wvA.w};
            #pragma unroll
            for (int cc = 0; cc < 4; ++cc) {
                float xv[4] = {xs[cc].x, xs[cc].y, xs[cc].z, xs[cc].w};
                #pragma unroll
                for (int p = 0; p < 4; ++p) {
                    aq[p] += wqr[cc] * xv[p];
                    ak[p] += wkr[cc] * xv[p];
                    av[p] += wvr[cc] * xv[p];
                }
            }
        }
        wqA = Wq[ia]; wkA = Wk[ia]; wvA = Wv[ia];   // reload after last use
        // ---- B: rows 4*c4+4 .. 4*c4+7 ----
        {
            float4 xs[4];
            #pragma unroll
            for (int r = 0; r < 4; ++r)
                xs[r] = *(const float4*)(sx + (c4 * 4 + 4 + r) * 16 + ph);
            float wqr[4] = {wqB.x, wqB.y, wqB.z, wqB.w};
            float wkr[4] = {wkB.x, wkB.y, wkB.z, wkB.w};
            float wvr[4] = {wvB.x, wvB.y, wvB.z, wvB.w};
            #pragma unroll
            for (int cc = 0; cc < 4; ++cc) {
                float xv[4] = {xs[cc].x, xs[cc].y, xs[cc].z, xs[cc].w};
                #pragma unroll
                for (int p = 0; p < 4; ++p) {
                    aq[p] += wqr[cc] * xv[p];
                    ak[p] += wkr[cc] * xv[p];
                    av[p] += wvr[cc] * xv[p];
                }
            }
        }
        wqB = Wq[ib]; wkB = Wk[ib]; wvB = Wv[ib];
    }
    float bq = qb[o], bk = kb[o], bv = vb[o];
    float* wrq = st + olocal * STS + ph;
    float* wrk = st + 64 * STS + olocal * STS + ph;
    float* wrv = st + 2 * 64 * STS + olocal * STS + ph;
    #pragma unroll
    for (int p = 0; p < 4; ++p) {
        wrq[p] = aq[p] + bq;
        wrk[p] = ak[p] + bk;
        wrv[p] = av[p] + bv;
    }
    __syncthreads();

    int pix = threadIdx.x & 15;
    int r4 = (threadIdx.x >> 4) * 4;
    int obase = osplit * 64;
    float* qd = q + b * CHW + obase * NPIX + pix0 + pix;
    float* kd = kbuf + b * CHW + obase * NPIX + pix0 + pix;
    float* vd = vbuf + b * CHW + obase * NPIX + pix0 + pix;
    #pragma unroll
    for (int i = 0; i < 4; ++i) {
        int r = r4 + i;
        qd[r * NPIX] = st[r * STS + pix];
        kd[r * NPIX] = st[64 * STS + r * STS + pix];
        vd[r * NPIX] = st[2 * 64 * STS + r * STS + pix];
    }
}

// ---------------- attn: per-(b,c,row-quarter) local attention (r7 form) ----
// K/V staged from unpadded buffers; halo synthesized from bias scalars.
// q prefetched one group ahead. All coords LOCAL to the quarter.
__global__ __launch_bounds__(256) void attn_kernel(
    const float* __restrict__ q, const float* __restrict__ kbuf,
    const float* __restrict__ vbuf,
    const float* __restrict__ kb, const float* __restrict__ vb,
    const float* __restrict__ rb, float* __restrict__ out)
{
    __shared__ float sK[20 * SKS];
    __shared__ float sV[21 * SKS];   // row 20 zeroed (read only with w=0)
    __shared__ float sW[4 * 64];
    int bid = blockIdx.x;
    int qpart = bid & 3;
    int bc = bid >> 2;
    int ch = bc & 127;
    const float* qc = q + bc * NPIX + 784 * qpart;
    const float* kc = kbuf + bc * NPIX;
    const float* vc = vbuf + bc * NPIX;
    float* oc = out + bc * NPIX + 784 * qpart;
    float kbias = kb[ch], vbias = vb[ch];
    int qr0 = 14 * qpart;

    for (int i = threadIdx.x; i < 20 * 62; i += 256) {
        int yy = i / 62, xx = i - yy * 62;
        int gy = qr0 + yy - 3;
        int gx = xx - 3;
        bool in = (gy >= 0) && (gy < 56) && (gx >= 0) && (gx < 56);
        int off = in ? gy * 56 + gx : 0;
        float kv = in ? kc[off] : kbias;
        float vv = in ? vc[off] : vbias;
        sK[yy * SKS + xx] = kv;
        sV[yy * SKS + xx] = vv;
    }
    for (int i = threadIdx.x; i < SKS; i += 256) sV[20 * SKS + i] = 0.f;

    int lane = threadIdx.x & 63;
    int wave = threadIdx.x >> 6;
    int k2 = min(lane, 48);
    int di = k2 / 7, dj = k2 - di * 7;
    float rbias = rb[di] + rb[7 + dj];
    int koff = di * SKS + dj;
    int t16 = lane & 15, p = lane >> 4;
    float* sWw = sW + wave * 64;

    // prefetch first group's q (global loads, no LDS dep -> before barrier)
    int ul0 = wave * 16;               // LOCAL pixel index within quarter
    int y0 = 0, x0 = ul0;
    float4 p0 = *(const float4*)(qc + ul0);
    float4 p1 = *(const float4*)(qc + ul0 + 4);
    float4 p2 = *(const float4*)(qc + ul0 + 8);
    float4 p3 = *(const float4*)(qc + ul0 + 12);
    __syncthreads();

    for (int gl = wave; gl < 49; gl += 4) {
        float4 q0 = p0, q1 = p1, q2 = p2, q3 = p3;
        if (gl + 4 < 49) {
            int un = ul0 + 64;
            p0 = *(const float4*)(qc + un);
            p1 = *(const float4*)(qc + un + 4);
            p2 = *(const float4*)(qc + un + 8);
            p3 = *(const float4*)(qc + un + 12);
        }
        float qa[16] = {q0.x, q0.y, q0.z, q0.w, q1.x, q1.y, q1.z, q1.w,
                        q2.x, q2.y, q2.z, q2.w, q3.x, q3.y, q3.z, q3.w};
        float qs = 0.f;
        #pragma unroll
        for (int t = 0; t < 16; ++t) qs += qa[t];

        // --- qk: compile-time-offset LDS reads (merge into ds_read2) -----
        float acc = 0.f;
        const float* kb_ = sK + y0 * SKS + x0 + koff;
        if (x0 != 48) {
            #pragma unroll
            for (int t = 0; t < 16; ++t) acc += qa[t] * kb_[t];
        } else {
            const float* kb2 = sK + (y0 + 1) * SKS + koff;
            #pragma unroll
            for (int t = 0; t < 8; ++t) acc += qa[t] * kb_[t];
            #pragma unroll
            for (int t = 0; t < 8; ++t) acc += qa[8 + t] * kb2[t];
        }
        float val = (lane < 49) ? (acc + qs * rbias) : -1e30f;

        // --- softmax over 49 via DPP (VALU pipe) -------------------------
        float mS = wave_max(val);
        float e = __expf(val - mS);
        float sS = wave_sum(e);
        float wgt = e * __builtin_amdgcn_rcpf(sS);
        sWw[lane] = wgt;                       // lanes 49..63 write 0 pad

        // --- PV: lane = (t, ki-row-pair p); LOCAL yt/xt ------------------
        int u = ul0 + t16;
        int yt = u / 56;
        int xt = u - yt * 56;
        const float* vbase = sV + yt * SKS + xt + p * (2 * SKS);
        const float* wbase = sWw + p * 14;
        float o0 = 0.f, o1 = 0.f;
        #pragma unroll
        for (int j = 0; j < 7; ++j) o0 += wbase[j] * vbase[j];
        #pragma unroll
        for (int j = 0; j < 7; ++j) o1 += wbase[7 + j] * vbase[SKS + j];
        float oacc = o0 + o1;
        oacc += __shfl_xor(oacc, 16);
        oacc += __shfl_xor(oacc, 32);
        if (lane < 16) oc[ul0 + lane] = oacc;

        // advance local coords: ul0 += 64 => y0 += 1, x0 += 8 (with carry)
        ul0 += 64;
        x0 += 8; y0 += 1;
        if (x0 >= 56) { x0 -= 56; ++y0; }
    }
}

extern "C" void kernel_launch(void* const* d_in, const int* in_sizes, int n_in,
                              void* d_out, int out_size, void* d_ws, size_t ws_size,
                              hipStream_t stream) {
    const float* x     = (const float*)d_in[0];
    const float* qw    = (const float*)d_in[1];
    const float* qb    = (const float*)d_in[2];
    const float* kw    = (const float*)d_in[3];
    const float* kb    = (const float*)d_in[4];
    const float* vw    = (const float*)d_in[5];
    const float* vb    = (const float*)d_in[6];
    const float* rel_h = (const float*)d_in[7];
    const float* rel_w = (const float*)d_in[8];
    float* out = (float*)d_out;

    float* ws   = (float*)d_ws;
    float* kbuf = ws;                    // 1605632
    float* vbuf = kbuf + 1605632;        // 1605632
    float* qbuf = vbuf + 1605632;        // 1605632
    float* w4q  = qbuf + 1605632;        // 16384
    float* w4k  = w4q + 16384;
    float* w4v  = w4k + 16384;
    float* rb   = w4v + 16384;           // 16

    prep_kernel<<<192, 256, 0, stream>>>(qw, kw, vw, rel_h, rel_w,
                                         w4q, w4k, w4v, rb);
    conv_kernel<<<1568, 256, 0, stream>>>(x, w4q, w4k, w4v, qb, kb, vb,
                                          qbuf, kbuf, vbuf);
    attn_kernel<<<2048, 256, 0, stream>>>(qbuf, kbuf, vbuf, kb, vb, rb, out);
}

// Round 13
// 76.372 us; speedup vs baseline: 3.5176x; 1.8156x over previous
//
#include <hip/hip_runtime.h>
#include <hip/hip_bf16.h>
#include <math.h>

#define NB    4
#define NC    128
#define NPIX  3136      // 56*56
#define CHW   401408    // 128*3136
#define KVP   3968      // padded K/V image: 62 rows x 64 stride
#define SKS   68        // LDS row stride for K/V tiles
#define STS   19        // conv transpose-buffer row stride (odd => bank-clean)

// ---------- DPP wave64 reduce helpers (VALU pipe, no DS) -------------------
template <int CTRL, int RM>
__device__ __forceinline__ float dpp_mov(float x, float old) {
    return __int_as_float(__builtin_amdgcn_update_dpp(
        __float_as_int(old), __float_as_int(x), CTRL, RM, 0xf, false));
}
__device__ __forceinline__ float wave_max(float x) {
    x = fmaxf(x, dpp_mov<0x111, 0xf>(x, x));   // row_shr:1
    x = fmaxf(x, dpp_mov<0x112, 0xf>(x, x));   // row_shr:2
    x = fmaxf(x, dpp_mov<0x114, 0xf>(x, x));   // row_shr:4
    x = fmaxf(x, dpp_mov<0x118, 0xf>(x, x));   // row_shr:8
    x = fmaxf(x, dpp_mov<0x142, 0xa>(x, x));   // row_bcast:15 -> rows 1,3
    x = fmaxf(x, dpp_mov<0x143, 0xc>(x, x));   // row_bcast:31 -> rows 2,3
    return __int_as_float(__builtin_amdgcn_readlane(__float_as_int(x), 63));
}
__device__ __forceinline__ float wave_sum(float x) {
    x = x + dpp_mov<0x111, 0xf>(x, 0.f);
    x = x + dpp_mov<0x112, 0xf>(x, 0.f);
    x = x + dpp_mov<0x114, 0xf>(x, 0.f);
    x = x + dpp_mov<0x118, 0xf>(x, 0.f);
    x = x + dpp_mov<0x142, 0xa>(x, 0.f);
    x = x + dpp_mov<0x143, 0xc>(x, 0.f);
    return __int_as_float(__builtin_amdgcn_readlane(__float_as_int(x), 63));
}

// ---------------- prep: weight pack + rel sums + padded-K/V halo fill ------
__global__ __launch_bounds__(256) void prep_kernel(
    const float* __restrict__ qw, const float* __restrict__ kw,
    const float* __restrict__ vw,
    const float* __restrict__ kb, const float* __restrict__ vb,
    const float* __restrict__ rel_h, const float* __restrict__ rel_w,
    float* __restrict__ kpad, float* __restrict__ vpad,
    float* __restrict__ w4q, float* __restrict__ w4k, float* __restrict__ w4v,
    float* __restrict__ rb)
{
    int idx = blockIdx.x * 256 + threadIdx.x;
    {   // halo: 708 positions per image, 512 images (grid == 362496 threads)
        int img = idx / 708;
        int hl = idx - img * 708;
        int p;
        if (hl < 186) {                    // rows 0..2, cols 0..61
            int r = hl / 62;
            p = r * 64 + (hl - r * 62);
        } else if (hl < 372) {             // rows 59..61, cols 0..61
            int j = hl - 186;
            int r = j / 62;
            p = (59 + r) * 64 + (j - r * 62);
        } else {                           // rows 3..58, cols {0,1,2,59,60,61}
            int j = hl - 372;
            int r = j / 6, cc = j - r * 6;
            p = (r + 3) * 64 + (cc < 3 ? cc : cc + 56);
        }
        int ch = img & 127;
        size_t o = (size_t)img * KVP + p;
        kpad[o] = kb[ch];
        vpad[o] = vb[ch];
    }
    if (idx < 3 * 16384) {
        int m = idx >> 14;
        int r = idx & 16383;          // dst-linear: ((c4*128 + o)*4 + cc)
        int cc = r & 3;
        int t = r >> 2;
        int o = t & 127;
        int c4 = t >> 7;
        const float* src = (m == 0) ? qw : (m == 1) ? kw : vw;
        float* dst = (m == 0) ? w4q : (m == 1) ? w4k : w4v;
        dst[r] = src[o * 128 + c4 * 4 + cc];
    }
    if (idx < 14) {
        const float* src = (idx < 7) ? rel_h : rel_w;
        int off = (idx < 7) ? idx : idx - 7;
        float s = 0.f;
        for (int c = 0; c < 64; ++c) s += src[c * 7 + off];
        rb[idx] = s;
    }
}

// ---------------- conv: fused 1x1 convs Q,K,V (fp32, r7 shape) -------------
// block = (b, 16-pixel tile). lane=o compute (coalesced W4 loads, depth-1
// prefetch, batched x reads); stride-19 LDS transpose; lane=pixel stores:
// q unpadded, K/V into padded stride-64 images.
__global__ __launch_bounds__(256) void conv_kernel(
    const float* __restrict__ x,
    const float* __restrict__ w4q, const float* __restrict__ w4k,
    const float* __restrict__ w4v,
    const float* __restrict__ qb, const float* __restrict__ kb,
    const float* __restrict__ vb,
    float* __restrict__ q, float* __restrict__ kpad, float* __restrict__ vpad)
{
    __shared__ float sx[128 * 16];       // [c][pix] 8KB
    __shared__ float st[3 * 128 * STS];  // q/k/v transpose planes, 28.5KB
    int bid = blockIdx.x;
    int tile = bid % 196;
    int b = bid / 196;
    int pix0 = tile * 16;
    const float* xb = x + b * CHW + pix0;

    for (int i = threadIdx.x; i < 512; i += 256) {
        int c = i >> 2, p4 = (i & 3) * 4;
        *(float4*)(sx + c * 16 + p4) = *(const float4*)(xb + c * NPIX + p4);
    }
    __syncthreads();

    int lane = threadIdx.x & 63;
    int wave = threadIdx.x >> 6;
    int o = wave * 32 + (lane & 31);
    int ph = (lane >> 5) * 8;
    const float4* Wq = (const float4*)w4q + o;
    const float4* Wk = (const float4*)w4k + o;
    const float4* Wv = (const float4*)w4v + o;

    float4 wqc = Wq[0], wkc = Wk[0], wvc = Wv[0];   // pipeline head
    float aq[8] = {}, ak[8] = {}, av[8] = {};
    #pragma unroll 1
    for (int c4 = 0; c4 < 32; ++c4) {
        float4 xs[8];
        #pragma unroll
        for (int cc = 0; cc < 4; ++cc) {
            xs[2 * cc]     = *(const float4*)(sx + (c4 * 4 + cc) * 16 + ph);
            xs[2 * cc + 1] = *(const float4*)(sx + (c4 * 4 + cc) * 16 + ph + 4);
        }
        float4 wq4 = wqc, wk4 = wkc, wv4 = wvc;
        if (c4 < 31) {   // prefetch next iter's weights (covered by FMAs)
            wqc = Wq[(c4 + 1) * 128];
            wkc = Wk[(c4 + 1) * 128];
            wvc = Wv[(c4 + 1) * 128];
        }
        float wqr[4] = {wq4.x, wq4.y, wq4.z, wq4.w};
        float wkr[4] = {wk4.x, wk4.y, wk4.z, wk4.w};
        float wvr[4] = {wv4.x, wv4.y, wv4.z, wv4.w};
        #pragma unroll
        for (int cc = 0; cc < 4; ++cc) {
            float4 xa = xs[2 * cc], xc = xs[2 * cc + 1];
            float xv[8] = {xa.x, xa.y, xa.z, xa.w, xc.x, xc.y, xc.z, xc.w};
            #pragma unroll
            for (int p = 0; p < 8; ++p) {
                aq[p] += wqr[cc] * xv[p];
                ak[p] += wkr[cc] * xv[p];
                av[p] += wvr[cc] * xv[p];
            }
        }
    }
    float bq = qb[o], bk = kb[o], bv = vb[o];
    float* wrq = st + o * STS + ph;
    float* wrk = st + 128 * STS + o * STS + ph;
    float* wrv = st + 2 * 128 * STS + o * STS + ph;
    #pragma unroll
    for (int p = 0; p < 8; ++p) {
        wrq[p] = aq[p] + bq;
        wrk[p] = ak[p] + bk;
        wrv[p] = av[p] + bv;
    }
    __syncthreads();

    int pix = threadIdx.x & 15;
    int o8 = (threadIdx.x >> 4) * 8;
    int pp = pix0 + pix;
    int yy = pp / 56, xx = pp - yy * 56;
    int po = (yy + 3) * 64 + xx + 3;                    // padded dest offset
    float* qd = q + b * CHW + pix0 + pix;
    float* kd = kpad + (size_t)b * 128 * KVP + po;
    float* vd = vpad + (size_t)b * 128 * KVP + po;
    #pragma unroll
    for (int i = 0; i < 8; ++i) {
        int r = o8 + i;
        qd[r * NPIX] = st[r * STS + pix];
        kd[(size_t)r * KVP] = st[128 * STS + r * STS + pix];
        vd[(size_t)r * KVP] = st[2 * 128 * STS + r * STS + pix];
    }
}

// ---------------- attn: per-(b,c,row-quarter) local attention --------------
// K/V staged from PADDED buffers with float4/float2 vector loads + aligned
// ds_write (no bounds logic). q prefetched one group ahead. Coords local.
__global__ __launch_bounds__(256) void attn_kernel(
    const float* __restrict__ q, const float* __restrict__ kpad,
    const float* __restrict__ vpad,
    const float* __restrict__ rb, float* __restrict__ out)
{
    __shared__ __align__(16) float sK[20 * SKS];
    __shared__ __align__(16) float sV[21 * SKS];   // row 20 zeroed
    __shared__ float sW[4 * 64];
    int bid = blockIdx.x;
    int qpart = bid & 3;
    int bc = bid >> 2;
    const float* qc = q + bc * NPIX + 784 * qpart;
    float* oc = out + bc * NPIX + 784 * qpart;
    int qr0 = 14 * qpart;
    const float* kp0 = kpad + (size_t)bc * KVP + qr0 * 64;
    const float* vp0 = vpad + (size_t)bc * KVP + qr0 * 64;

    // staging: 20 rows x (15 float4 + 1 float2) per buffer
    for (int i = threadIdx.x; i < 320; i += 256) {
        int yy = i >> 4, c16 = i & 15;
        if (c16 < 15) {
            float4 kv4 = *(const float4*)(kp0 + yy * 64 + c16 * 4);
            float4 vv4 = *(const float4*)(vp0 + yy * 64 + c16 * 4);
            *(float4*)(sK + yy * SKS + c16 * 4) = kv4;
            *(float4*)(sV + yy * SKS + c16 * 4) = vv4;
        } else {
            float2 kv2 = *(const float2*)(kp0 + yy * 64 + 60);
            float2 vv2 = *(const float2*)(vp0 + yy * 64 + 60);
            *(float2*)(sK + yy * SKS + 60) = kv2;
            *(float2*)(sV + yy * SKS + 60) = vv2;
        }
    }
    for (int i = threadIdx.x; i < SKS; i += 256) sV[20 * SKS + i] = 0.f;

    int lane = threadIdx.x & 63;
    int wave = threadIdx.x >> 6;
    int k2 = min(lane, 48);
    int di = k2 / 7, dj = k2 - di * 7;
    float rbias = rb[di] + rb[7 + dj];
    int koff = di * SKS + dj;
    int t16 = lane & 15, p = lane >> 4;
    float* sWw = sW + wave * 64;

    // prefetch first group's q (global loads, no LDS dep -> before barrier)
    int ul0 = wave * 16;               // LOCAL pixel index within quarter
    int y0 = 0, x0 = ul0;
    float4 p0 = *(const float4*)(qc + ul0);
    float4 p1 = *(const float4*)(qc + ul0 + 4);
    float4 p2 = *(const float4*)(qc + ul0 + 8);
    float4 p3 = *(const float4*)(qc + ul0 + 12);
    __syncthreads();

    for (int gl = wave; gl < 49; gl += 4) {
        float4 q0 = p0, q1 = p1, q2 = p2, q3 = p3;
        if (gl + 4 < 49) {
            int un = ul0 + 64;
            p0 = *(const float4*)(qc + un);
            p1 = *(const float4*)(qc + un + 4);
            p2 = *(const float4*)(qc + un + 8);
            p3 = *(const float4*)(qc + un + 12);
        }
        float qa[16] = {q0.x, q0.y, q0.z, q0.w, q1.x, q1.y, q1.z, q1.w,
                        q2.x, q2.y, q2.z, q2.w, q3.x, q3.y, q3.z, q3.w};
        float qs = 0.f;
        #pragma unroll
        for (int t = 0; t < 16; ++t) qs += qa[t];

        // --- qk: compile-time-offset LDS reads (merge into ds_read2) -----
        float acc = 0.f;
        const float* kb_ = sK + y0 * SKS + x0 + koff;
        if (x0 != 48) {
            #pragma unroll
            for (int t = 0; t < 16; ++t) acc += qa[t] * kb_[t];
        } else {
            const float* kb2 = sK + (y0 + 1) * SKS + koff;
            #pragma unroll
            for (int t = 0; t < 8; ++t) acc += qa[t] * kb_[t];
            #pragma unroll
            for (int t = 0; t < 8; ++t) acc += qa[8 + t] * kb2[t];
        }
        float val = (lane < 49) ? (acc + qs * rbias) : -1e30f;

        // --- softmax over 49 via DPP (VALU pipe) -------------------------
        float mS = wave_max(val);
        float e = __expf(val - mS);
        float sS = wave_sum(e);
        float wgt = e * __builtin_amdgcn_rcpf(sS);
        sWw[lane] = wgt;                       // lanes 49..63 write 0 pad

        // --- PV: lane = (t, ki-row-pair p); LOCAL yt/xt ------------------
        int u = ul0 + t16;
        int yt = u / 56;
        int xt = u - yt * 56;
        const float* vbase = sV + yt * SKS + xt + p * (2 * SKS);
        const float* wbase = sWw + p * 14;
        float o0 = 0.f, o1 = 0.f;
        #pragma unroll
        for (int j = 0; j < 7; ++j) o0 += wbase[j] * vbase[j];
        #pragma unroll
        for (int j = 0; j < 7; ++j) o1 += wbase[7 + j] * vbase[SKS + j];
        float oacc = o0 + o1;
        oacc += __shfl_xor(oacc, 16);
        oacc += __shfl_xor(oacc, 32);
        if (lane < 16) oc[ul0 + lane] = oacc;

        // advance local coords: ul0 += 64 => y0 += 1, x0 += 8 (with carry)
        ul0 += 64;
        x0 += 8; y0 += 1;
        if (x0 >= 56) { x0 -= 56; ++y0; }
    }
}

extern "C" void kernel_launch(void* const* d_in, const int* in_sizes, int n_in,
                              void* d_out, int out_size, void* d_ws, size_t ws_size,
                              hipStream_t stream) {
    const float* x     = (const float*)d_in[0];
    const float* qw    = (const float*)d_in[1];
    const float* qb    = (const float*)d_in[2];
    const float* kw    = (const float*)d_in[3];
    const float* kb    = (const float*)d_in[4];
    const float* vw    = (const float*)d_in[5];
    const float* vb    = (const float*)d_in[6];
    const float* rel_h = (const float*)d_in[7];
    const float* rel_w = (const float*)d_in[8];
    float* out = (float*)d_out;

    float* ws   = (float*)d_ws;
    float* kpad = ws;                    // 512*3968 = 2031616
    float* vpad = kpad + 2031616;        // 2031616
    float* qbuf = vpad + 2031616;        // 1605632
    float* w4q  = qbuf + 1605632;        // 16384
    float* w4k  = w4q + 16384;
    float* w4v  = w4k + 16384;
    float* rb   = w4v + 16384;           // 16

    prep_kernel<<<1416, 256, 0, stream>>>(qw, kw, vw, kb, vb, rel_h, rel_w,
                                          kpad, vpad, w4q, w4k, w4v, rb);
    conv_kernel<<<784, 256, 0, stream>>>(x, w4q, w4k, w4v, qb, kb, vb,
                                         qbuf, kpad, vpad);
    attn_kernel<<<2048, 256, 0, stream>>>(qbuf, kpad, vpad, rb, out);
}

// Round 14
// 70.045 us; speedup vs baseline: 3.8354x; 1.0903x over previous
//
#include <hip/hip_runtime.h>
#include <hip/hip_bf16.h>
#include <math.h>

#define NB    4
#define NC    128
#define NPIX  3136      // 56*56
#define CHW   401408    // 128*3136
#define SKS   68        // LDS row stride for K/V tiles
#define STS   19        // conv transpose-buffer row stride (odd => bank-clean)

// ---------- DPP wave64 sum (VALU pipe, no DS) ------------------------------
template <int CTRL, int RM>
__device__ __forceinline__ float dpp_mov(float x, float old) {
    return __int_as_float(__builtin_amdgcn_update_dpp(
        __float_as_int(old), __float_as_int(x), CTRL, RM, 0xf, false));
}
__device__ __forceinline__ float wave_sum(float x) {
    x = x + dpp_mov<0x111, 0xf>(x, 0.f);   // row_shr:1
    x = x + dpp_mov<0x112, 0xf>(x, 0.f);   // row_shr:2
    x = x + dpp_mov<0x114, 0xf>(x, 0.f);   // row_shr:4
    x = x + dpp_mov<0x118, 0xf>(x, 0.f);   // row_shr:8
    x = x + dpp_mov<0x142, 0xa>(x, 0.f);   // row_bcast:15 -> rows 1,3
    x = x + dpp_mov<0x143, 0xc>(x, 0.f);   // row_bcast:31 -> rows 2,3
    return __int_as_float(__builtin_amdgcn_readlane(__float_as_int(x), 63));
}

// 16-term QK dot, 2 chains; kp2 = continuation pointer (handles row wrap)
__device__ __forceinline__ float qk16(const float* kp, const float* kp2,
                                      float4 r0, float4 r1, float4 r2, float4 r3) {
    float a0, a1;
    a0  = r0.x * kp[0];   a1  = r0.y * kp[1];
    a0 += r0.z * kp[2];   a1 += r0.w * kp[3];
    a0 += r1.x * kp[4];   a1 += r1.y * kp[5];
    a0 += r1.z * kp[6];   a1 += r1.w * kp[7];
    a0 += r2.x * kp2[0];  a1 += r2.y * kp2[1];
    a0 += r2.z * kp2[2];  a1 += r2.w * kp2[3];
    a0 += r3.x * kp2[4];  a1 += r3.y * kp2[5];
    a0 += r3.z * kp2[6];  a1 += r3.w * kp2[7];
    return a0 + a1;
}
__device__ __forceinline__ float sum16(float4 r0, float4 r1, float4 r2, float4 r3) {
    return (((r0.x + r0.y) + (r0.z + r0.w)) + ((r1.x + r1.y) + (r1.z + r1.w)))
         + (((r2.x + r2.y) + (r2.z + r2.w)) + ((r3.x + r3.y) + (r3.z + r3.w)));
}

// ---------------- prep: weight pack + rel sums (r7 form) --------------------
__global__ __launch_bounds__(256) void prep_kernel(
    const float* __restrict__ qw, const float* __restrict__ kw,
    const float* __restrict__ vw,
    const float* __restrict__ rel_h, const float* __restrict__ rel_w,
    float* __restrict__ w4q, float* __restrict__ w4k, float* __restrict__ w4v,
    float* __restrict__ rb)
{
    int idx = blockIdx.x * 256 + threadIdx.x;
    if (idx < 3 * 16384) {
        int m = idx >> 14;
        int r = idx & 16383;          // dst-linear: ((c4*128 + o)*4 + cc)
        int cc = r & 3;
        int t = r >> 2;
        int o = t & 127;
        int c4 = t >> 7;
        const float* src = (m == 0) ? qw : (m == 1) ? kw : vw;
        float* dst = (m == 0) ? w4q : (m == 1) ? w4k : w4v;
        dst[r] = src[o * 128 + c4 * 4 + cc];
    }
    if (idx < 14) {
        const float* src = (idx < 7) ? rel_h : rel_w;
        int off = (idx < 7) ? idx : idx - 7;
        float s = 0.f;
        for (int c = 0; c < 64; ++c) s += src[c * 7 + off];
        rb[idx] = s;
    }
}

// ---------------- conv: fused 1x1 convs Q,K,V (fp32, r7 verbatim) ----------
__global__ __launch_bounds__(256) void conv_kernel(
    const float* __restrict__ x,
    const float* __restrict__ w4q, const float* __restrict__ w4k,
    const float* __restrict__ w4v,
    const float* __restrict__ qb, const float* __restrict__ kb,
    const float* __restrict__ vb,
    float* __restrict__ q, float* __restrict__ kbuf, float* __restrict__ vbuf)
{
    __shared__ float sx[128 * 16];       // [c][pix] 8KB
    __shared__ float st[3 * 128 * STS];  // q/k/v transpose planes, 28.5KB
    int bid = blockIdx.x;
    int tile = bid % 196;
    int b = bid / 196;
    int pix0 = tile * 16;
    const float* xb = x + b * CHW + pix0;

    for (int i = threadIdx.x; i < 512; i += 256) {
        int c = i >> 2, p4 = (i & 3) * 4;
        *(float4*)(sx + c * 16 + p4) = *(const float4*)(xb + c * NPIX + p4);
    }
    __syncthreads();

    int lane = threadIdx.x & 63;
    int wave = threadIdx.x >> 6;
    int o = wave * 32 + (lane & 31);
    int ph = (lane >> 5) * 8;
    const float4* Wq = (const float4*)w4q + o;
    const float4* Wk = (const float4*)w4k + o;
    const float4* Wv = (const float4*)w4v + o;

    float4 wqc = Wq[0], wkc = Wk[0], wvc = Wv[0];   // pipeline head
    float aq[8] = {}, ak[8] = {}, av[8] = {};
    #pragma unroll 1
    for (int c4 = 0; c4 < 32; ++c4) {
        float4 xs[8];
        #pragma unroll
        for (int cc = 0; cc < 4; ++cc) {
            xs[2 * cc]     = *(const float4*)(sx + (c4 * 4 + cc) * 16 + ph);
            xs[2 * cc + 1] = *(const float4*)(sx + (c4 * 4 + cc) * 16 + ph + 4);
        }
        float4 wq4 = wqc, wk4 = wkc, wv4 = wvc;
        if (c4 < 31) {   // prefetch next iter's weights (covered by FMAs)
            wqc = Wq[(c4 + 1) * 128];
            wkc = Wk[(c4 + 1) * 128];
            wvc = Wv[(c4 + 1) * 128];
        }
        float wqr[4] = {wq4.x, wq4.y, wq4.z, wq4.w};
        float wkr[4] = {wk4.x, wk4.y, wk4.z, wk4.w};
        float wvr[4] = {wv4.x, wv4.y, wv4.z, wv4.w};
        #pragma unroll
        for (int cc = 0; cc < 4; ++cc) {
            float4 xa = xs[2 * cc], xc = xs[2 * cc + 1];
            float xv[8] = {xa.x, xa.y, xa.z, xa.w, xc.x, xc.y, xc.z, xc.w};
            #pragma unroll
            for (int p = 0; p < 8; ++p) {
                aq[p] += wqr[cc] * xv[p];
                ak[p] += wkr[cc] * xv[p];
                av[p] += wvr[cc] * xv[p];
            }
        }
    }
    float bq = qb[o], bk = kb[o], bv = vb[o];
    float* wrq = st + o * STS + ph;
    float* wrk = st + 128 * STS + o * STS + ph;
    float* wrv = st + 2 * 128 * STS + o * STS + ph;
    #pragma unroll
    for (int p = 0; p < 8; ++p) {
        wrq[p] = aq[p] + bq;
        wrk[p] = ak[p] + bk;
        wrv[p] = av[p] + bv;
    }
    __syncthreads();

    int pix = threadIdx.x & 15;
    int o8 = (threadIdx.x >> 4) * 8;
    float* qd = q + b * CHW + pix0 + pix;
    float* kd = kbuf + b * CHW + pix0 + pix;
    float* vd = vbuf + b * CHW + pix0 + pix;
    #pragma unroll
    for (int i = 0; i < 8; ++i) {
        int r = o8 + i;
        qd[r * NPIX] = st[r * STS + pix];
        kd[r * NPIX] = st[128 * STS + r * STS + pix];
        vd[r * NPIX] = st[2 * 128 * STS + r * STS + pix];
    }
}

// ---------------- attn: per-(b,c,row-quarter); shift-softmax (no max) ------
// Softmax shift u = qs*rbsel (rbsel = rbmax if qs>0 else rbmin) is uniform
// across the 49 lanes -> exact softmax, no DPP max-reduce, bounded exponents.
__global__ __launch_bounds__(256) void attn_kernel(
    const float* __restrict__ q, const float* __restrict__ kbuf,
    const float* __restrict__ vbuf,
    const float* __restrict__ kb, const float* __restrict__ vb,
    const float* __restrict__ rb, float* __restrict__ out)
{
    __shared__ float sK[20 * SKS];
    __shared__ float sV[21 * SKS];   // row 20 zeroed (read only with w=0)
    __shared__ float sW[4 * 64];
    int bid = blockIdx.x;
    int qpart = bid & 3;
    int bc = bid >> 2;
    int ch = bc & 127;
    const float* qc = q + bc * NPIX + 784 * qpart;
    const float* kc = kbuf + bc * NPIX;
    const float* vc = vbuf + bc * NPIX;
    float* oc = out + bc * NPIX + 784 * qpart;
    float kbias = kb[ch], vbias = vb[ch];
    int qr0 = 14 * qpart;

    for (int i = threadIdx.x; i < 20 * 62; i += 256) {
        int yy = i / 62, xx = i - yy * 62;
        int gy = qr0 + yy - 3;
        int gx = xx - 3;
        bool in = (gy >= 0) && (gy < 56) && (gx >= 0) && (gx < 56);
        int off = in ? gy * 56 + gx : 0;
        float kv = in ? kc[off] : kbias;
        float vv = in ? vc[off] : vbias;
        sK[yy * SKS + xx] = kv;
        sV[yy * SKS + xx] = vv;
    }
    for (int i = threadIdx.x; i < SKS; i += 256) sV[20 * SKS + i] = 0.f;

    int lane = threadIdx.x & 63;
    int wave = threadIdx.x >> 6;
    int k2 = min(lane, 48);
    int di = k2 / 7, dj = k2 - di * 7;
    float rbias = rb[di] + rb[7 + dj];
    int koff = di * SKS + dj;
    int t16 = lane & 15, p = lane >> 4;
    float* sWw = sW + wave * 64;

    // uniform rbias extrema (L1-hot scalar loads, once per block)
    float rhM = rb[0], rhm = rb[0];
    #pragma unroll
    for (int i = 1; i < 7; ++i) { rhM = fmaxf(rhM, rb[i]); rhm = fminf(rhm, rb[i]); }
    float rwM = rb[7], rwm = rb[7];
    #pragma unroll
    for (int i = 8; i < 14; ++i) { rwM = fmaxf(rwM, rb[i]); rwm = fminf(rwm, rb[i]); }
    float rdMax = rbias - (rhM + rwM);   // <= 0 per lane
    float rdMin = rbias - (rhm + rwm);   // >= 0 per lane

    // prefetch first group's q (global loads, no LDS dep -> before barrier)
    int ul0 = wave * 16;               // LOCAL pixel index within quarter
    int y0 = 0, x0 = ul0;
    float4 p0 = *(const float4*)(qc + ul0);
    float4 p1 = *(const float4*)(qc + ul0 + 4);
    float4 p2 = *(const float4*)(qc + ul0 + 8);
    float4 p3 = *(const float4*)(qc + ul0 + 12);
    __syncthreads();

    for (int gl = wave; gl < 49; gl += 4) {
        // --- QK (2 chains) + qs (tree), straight from prefetch regs ------
        float qs = sum16(p0, p1, p2, p3);
        const float* kp = sK + y0 * SKS + x0 + koff;
        int d2 = (x0 == 48) ? (SKS - 48) : 8;          // row-wrap continuation
        float acc = qk16(kp, kp + d2, p0, p1, p2, p3);

        // --- reload q regs for group gl+4 (after last use) ---------------
        if (gl + 4 < 49) {
            int un = ul0 + 64;
            p0 = *(const float4*)(qc + un);
            p1 = *(const float4*)(qc + un + 4);
            p2 = *(const float4*)(qc + un + 8);
            p3 = *(const float4*)(qc + un + 12);
        }

        // --- shift-softmax: u = qs*rbsel (uniform) -> no max reduce ------
        float rd = (qs > 0.f) ? rdMax : rdMin;
        float ex = fmaf(qs, rd, acc);                  // val - u <= acc
        float e = (lane < 49) ? __expf(ex) : 0.f;
        float sS = wave_sum(e);
        float wgt = e * __builtin_amdgcn_rcpf(sS);
        sWw[lane] = wgt;                               // lanes 49..63 write 0

        // --- PV: lane = (t, ki-row-pair p) -------------------------------
        int u = ul0 + t16;
        int yt = u / 56;
        int xt = u - yt * 56;
        const float* vbase = sV + yt * SKS + xt + p * (2 * SKS);
        const float* wbase = sWw + p * 14;
        float o0 = 0.f, o1 = 0.f;
        #pragma unroll
        for (int j = 0; j < 7; ++j) o0 += wbase[j] * vbase[j];
        #pragma unroll
        for (int j = 0; j < 7; ++j) o1 += wbase[7 + j] * vbase[SKS + j];
        float oacc = o0 + o1;
        oacc += __shfl_xor(oacc, 16);
        oacc += __shfl_xor(oacc, 32);
        if (lane < 16) oc[ul0 + lane] = oacc;

        // advance local coords: ul0 += 64 => y0 += 1, x0 += 8 (with carry)
        ul0 += 64;
        x0 += 8; y0 += 1;
        if (x0 >= 56) { x0 -= 56; ++y0; }
    }
}

extern "C" void kernel_launch(void* const* d_in, const int* in_sizes, int n_in,
                              void* d_out, int out_size, void* d_ws, size_t ws_size,
                              hipStream_t stream) {
    const float* x     = (const float*)d_in[0];
    const float* qw    = (const float*)d_in[1];
    const float* qb    = (const float*)d_in[2];
    const float* kw    = (const float*)d_in[3];
    const float* kb    = (const float*)d_in[4];
    const float* vw    = (const float*)d_in[5];
    const float* vb    = (const float*)d_in[6];
    const float* rel_h = (const float*)d_in[7];
    const float* rel_w = (const float*)d_in[8];
    float* out = (float*)d_out;

    float* ws   = (float*)d_ws;
    float* kbuf = ws;                    // 1605632
    float* vbuf = kbuf + 1605632;        // 1605632
    float* qbuf = vbuf + 1605632;        // 1605632
    float* w4q  = qbuf + 1605632;        // 16384
    float* w4k  = w4q + 16384;
    float* w4v  = w4k + 16384;
    float* rb   = w4v + 16384;           // 16

    prep_kernel<<<192, 256, 0, stream>>>(qw, kw, vw, rel_h, rel_w,
                                         w4q, w4k, w4v, rb);
    conv_kernel<<<784, 256, 0, stream>>>(x, w4q, w4k, w4v, qb, kb, vb,
                                         qbuf, kbuf, vbuf);
    attn_kernel<<<2048, 256, 0, stream>>>(qbuf, kbuf, vbuf, kb, vb, rb, out);
}